// Round 8
// baseline (2989.149 us; speedup 1.0000x reference)
//
#include <hip/hip_runtime.h>
#include <math.h>

// MultiRNNCell: 2-layer LSTM-imputation scan. B=64, T=128, D=256, H=1024.
// R7: attack endpoint data movement (not sync).
//  - 512-thread blocks, 2-way K-split (waves 0-3 lower K half, 4-7 upper),
//    LDS reduction of partial accumulators -> 2 waves/SIMD -> 2x outstanding
//    misses for the latency-bound h/h0 broadcast loads.
//  - producer stores: LDS-transpose then 128x dwordx4 sc0 sc1 write-through
//    (vs 1024x 2B) -> drain is ~1 ack round trip.
//  - per-wave half-flag polling (no barrier in waits), ring buffers, plain
//    cached consumer loads, fence-free (carried from R6).
// 144 blocks, 134KB LDS -> 1 block/CU. Dead forget gate removed; layer1
// weight fold W1 = Wih1+Whh1.

#define B_ 64
#define T_ 128
#define D_ 256
#define H_ 1024

#define NL0 64
#define NL1 64
#define NEST 16
#define NBLK (NL0 + NL1 + NEST)   // 144

#define KS0 40          // layer0 frag ksteps: 0-7 imputed (D=256), 8-39 h (H=1024)
#define KS1 32          // layer1 ksteps (H=1024)
#define KSE 32          // est ksteps (H=1024)

#define RS_H   ((size_t)B_ * H_)   // 128 KB per ring slot
#define RS_IMP ((size_t)B_ * D_)   // 32 KB per ring slot

typedef __attribute__((ext_vector_type(8))) short short8;   // 8 bf16
typedef __attribute__((ext_vector_type(4))) float floatx4;  // MFMA C/D

__device__ __forceinline__ unsigned short f2bf(float x) {
    union { float f; unsigned u; } v; v.f = x;
    unsigned r = v.u + 0x7fffu + ((v.u >> 16) & 1u);  // RNE
    return (unsigned short)(r >> 16);
}
__device__ __forceinline__ float sigmoidf_(float x) { return 1.0f / (1.0f + expf(-x)); }

// 16B write-through store to the MALL coherence point
__device__ __forceinline__ void st16_sc(void* p, short8 v) {
    asm volatile("global_store_dwordx4 %0, %1, off sc0 sc1"
                 :: "v"(p), "v"(v) : "memory");
}
__device__ __forceinline__ void vm_drain() {
    asm volatile("s_waitcnt vmcnt(0)" ::: "memory");
}

// per-wave half polls: wave kh needs producer chunks [kh*32, kh*32+32) etc.
__device__ __forceinline__ void poll32(const int* flags, int kh) {
    int idx = kh * 32 + (threadIdx.x & 31);
    while (__hip_atomic_load(flags + idx, __ATOMIC_RELAXED,
                             __HIP_MEMORY_SCOPE_AGENT) != 1) {}
}
__device__ __forceinline__ void poll8(const int* flags, int kh) {
    int idx = kh * 8 + (threadIdx.x & 7);
    while (__hip_atomic_load(flags + idx, __ATOMIC_RELAXED,
                             __HIP_MEMORY_SCOPE_AGENT) != 1) {}
}
// all waves' sc1 stores drained individually (vm_drain) before this barrier
__device__ __forceinline__ void signal_flag(int* flag) {
    __syncthreads();
    if (threadIdx.x == 0)
        __hip_atomic_store(flag, 1, __ATOMIC_RELAXED, __HIP_MEMORY_SCOPE_AGENT);
}

#define MFMA __builtin_amdgcn_mfma_f32_16x16x32_bf16

__global__ __launch_bounds__(512, 1) void k_fused(
    const float* __restrict__ Wih0, const float* __restrict__ Whh0,
    const float* __restrict__ bih0, const float* __restrict__ bhh0,
    const float* __restrict__ Wih1, const float* __restrict__ Whh1,
    const float* __restrict__ bih1, const float* __restrict__ bhh1,
    const float* __restrict__ Wout, const float* __restrict__ bout,
    const float* __restrict__ X, const float* __restrict__ Mm,
    unsigned short* __restrict__ hR,    // (T_+1) slots
    unsigned short* __restrict__ h0R,   // T_ slots
    unsigned short* __restrict__ impR,  // T_ slots
    int* __restrict__ fL1, int* __restrict__ fL0, int* __restrict__ fE,
    float* __restrict__ out)
{
    __shared__ unsigned short ldsW[3 * KS0 * 64 * 8];   // 120 KB weight frags
    __shared__ float          redZ[4 * 64 * 12];        // 12 KB k-split reduce
    __shared__ unsigned short ldsT[64 * 16];            // 2 KB store transpose

    const int tid  = threadIdx.x;
    const int lane = tid & 63;
    const int wv   = tid >> 6;        // 0..7
    const int mt   = wv & 3;          // m-tile (16 batch rows)
    const int kh   = wv >> 2;         // k-half
    const int m0   = mt * 16;
    const int r16  = lane & 15, q = lane >> 4;
    const int bx   = blockIdx.x;
    const unsigned short* lfrag = ldsW + lane * 8;   // + fragIdx*512

    // ---- one-time: fp32 weights -> bf16 LDS fragment order ----
    if (bx < NL0) {
        int n0 = bx * 16;
        for (int idx = wv; idx < 3 * KS0; idx += 8) {
            int gi = idx / KS0, k = idx % KS0;
            int grow = (gi == 0) ? 0 : (gi == 1 ? 2 * H_ : 3 * H_);
            int row = grow + n0 + r16;
            const float* src = (k < 8) ? (Wih0 + (size_t)row * D_ + k * 32 + q * 8)
                                       : (Whh0 + (size_t)row * H_ + (k - 8) * 32 + q * 8);
            short8 w;
            #pragma unroll
            for (int j = 0; j < 8; ++j) w[j] = (short)f2bf(src[j]);
            *(short8*)(ldsW + ((size_t)idx * 64 + lane) * 8) = w;
        }
    } else if (bx < NL0 + NL1) {
        int n0 = (bx - NL0) * 16;
        for (int idx = wv; idx < 3 * KS1; idx += 8) {
            int gi = idx / KS1, k = idx % KS1;
            int grow = (gi == 0) ? 0 : (gi == 1 ? 2 * H_ : 3 * H_);
            size_t o = (size_t)(grow + n0 + r16) * H_ + k * 32 + q * 8;
            short8 w;
            #pragma unroll
            for (int j = 0; j < 8; ++j) w[j] = (short)f2bf(Wih1[o + j] + Whh1[o + j]);
            *(short8*)(ldsW + ((size_t)idx * 64 + lane) * 8) = w;
        }
    } else {
        int d0 = (bx - NL0 - NL1) * 16;
        for (int idx = wv; idx < KSE; idx += 8) {
            const float* src = Wout + (size_t)(d0 + r16) * H_ + idx * 32 + q * 8;
            short8 w;
            #pragma unroll
            for (int j = 0; j < 8; ++j) w[j] = (short)f2bf(src[j]);
            *(short8*)(ldsW + ((size_t)idx * 64 + lane) * 8) = w;
        }
    }
    __syncthreads();

    if (bx < NL0) {
        // =============== layer-0 blocks ===============
        const int n0 = bx * 16;
        const int n  = n0 + r16;
        float bi = 0, bg = 0, bo = 0;
        if (kh == 0) {
            bi = bih0[n] + bhh0[n];
            bg = bih0[2 * H_ + n] + bhh0[2 * H_ + n];
            bo = bih0[3 * H_ + n] + bhh0[3 * H_ + n];
        }
        for (int t = 0; t < T_; ++t) {
            poll32(fL1 + (size_t)t * 64, kh);         // my half of h(t-1)
            floatx4 ai = {0.f,0.f,0.f,0.f}, ag = ai, ao = ai;
            {   // h-part, ksteps kh*16..kh*16+15
                const unsigned short* aB = hR + (size_t)t * RS_H + (m0 + r16) * H_ + q * 8;
                short8 af[16];
                #pragma unroll
                for (int k = 0; k < 16; ++k) af[k] = *(const short8*)(aB + (kh * 16 + k) * 32);
                #pragma unroll
                for (int k = 0; k < 16; ++k) {
                    int f = 8 + kh * 16 + k;
                    ai = MFMA(af[k], *(const short8*)(lfrag + (0*KS0 + f)*512), ai, 0,0,0);
                    ag = MFMA(af[k], *(const short8*)(lfrag + (1*KS0 + f)*512), ag, 0,0,0);
                    ao = MFMA(af[k], *(const short8*)(lfrag + (2*KS0 + f)*512), ao, 0,0,0);
                }
            }
            poll8(fE + (size_t)t * 16, kh);           // my half of imputed(t)
            {   // imputed part, ksteps kh*4..kh*4+3
                const unsigned short* aB = impR + (size_t)t * RS_IMP + (m0 + r16) * D_ + q * 8;
                short8 am[4];
                #pragma unroll
                for (int k = 0; k < 4; ++k) am[k] = *(const short8*)(aB + (kh * 4 + k) * 32);
                #pragma unroll
                for (int k = 0; k < 4; ++k) {
                    int f = kh * 4 + k;
                    ai = MFMA(am[k], *(const short8*)(lfrag + (0*KS0 + f)*512), ai, 0,0,0);
                    ag = MFMA(am[k], *(const short8*)(lfrag + (1*KS0 + f)*512), ag, 0,0,0);
                    ao = MFMA(am[k], *(const short8*)(lfrag + (2*KS0 + f)*512), ao, 0,0,0);
                }
            }
            if (kh == 1) {
                float* z = redZ + ((size_t)mt * 64 + lane) * 12;
                #pragma unroll
                for (int r = 0; r < 4; ++r) { z[r] = ai[r]; z[4+r] = ag[r]; z[8+r] = ao[r]; }
            }
            __syncthreads();                          // sync1: redZ ready
            if (kh == 0) {
                const float* z = redZ + ((size_t)mt * 64 + lane) * 12;
                #pragma unroll
                for (int r = 0; r < 4; ++r) {
                    float c = sigmoidf_(ai[r] + z[r] + bi) * tanhf(ag[r] + z[4+r] + bg);
                    float h = sigmoidf_(ao[r] + z[8+r] + bo) * tanhf(c);
                    ldsT[(m0 + q * 4 + r) * 16 + r16] = f2bf(h);
                }
            }
            __syncthreads();                          // sync2: ldsT ready
            if (tid < 128) {
                short8 v = *(const short8*)(ldsT + tid * 8);
                st16_sc(h0R + (size_t)t * RS_H + (size_t)(tid >> 1) * H_ + n0 + (tid & 1) * 8, v);
            }
            vm_drain();
            signal_flag(fL0 + (size_t)t * 64 + bx);   // sync3
        }
    } else if (bx < NL0 + NL1) {
        // =============== layer-1 blocks ===============
        const int j  = bx - NL0;
        const int n0 = j * 16;
        const int n  = n0 + r16;
        float bi = 0, bg = 0, bo = 0;
        if (kh == 0) {
            bi = bih1[n] + bhh1[n];
            bg = bih1[2 * H_ + n] + bhh1[2 * H_ + n];
            bo = bih1[3 * H_ + n] + bhh1[3 * H_ + n];
        }
        // h(-1) = 0 into hR slot 0
        if (tid < 128) {
            short8 z = {0,0,0,0,0,0,0,0};
            st16_sc(hR + (size_t)(tid >> 1) * H_ + n0 + (tid & 1) * 8, z);
        }
        vm_drain();
        signal_flag(fL1 + j);
        for (int t = 0; t < T_; ++t) {
            poll32(fL0 + (size_t)t * 64, kh);         // my half of h0(t)
            floatx4 li = {0.f,0.f,0.f,0.f}, lg = li, lo = li;
            const unsigned short* aB = h0R + (size_t)t * RS_H + (m0 + r16) * H_ + q * 8;
            short8 af[16];
            #pragma unroll
            for (int k = 0; k < 16; ++k) af[k] = *(const short8*)(aB + (kh * 16 + k) * 32);
            #pragma unroll
            for (int k = 0; k < 16; ++k) {
                int f = kh * 16 + k;
                li = MFMA(af[k], *(const short8*)(lfrag + (0*KS1 + f)*512), li, 0,0,0);
                lg = MFMA(af[k], *(const short8*)(lfrag + (1*KS1 + f)*512), lg, 0,0,0);
                lo = MFMA(af[k], *(const short8*)(lfrag + (2*KS1 + f)*512), lo, 0,0,0);
            }
            if (kh == 1) {
                float* z = redZ + ((size_t)mt * 64 + lane) * 12;
                #pragma unroll
                for (int r = 0; r < 4; ++r) { z[r] = li[r]; z[4+r] = lg[r]; z[8+r] = lo[r]; }
            }
            __syncthreads();                          // sync1
            float hv[4];
            if (kh == 0) {
                const float* z = redZ + ((size_t)mt * 64 + lane) * 12;
                #pragma unroll
                for (int r = 0; r < 4; ++r) {
                    float c = sigmoidf_(li[r] + z[r] + bi) * tanhf(lg[r] + z[4+r] + bg);
                    hv[r] = sigmoidf_(lo[r] + z[8+r] + bo) * tanhf(c);
                    ldsT[(m0 + q * 4 + r) * 16 + r16] = f2bf(hv[r]);
                }
            }
            __syncthreads();                          // sync2
            if (tid < 128) {
                short8 v = *(const short8*)(ldsT + tid * 8);
                st16_sc(hR + (size_t)(t + 1) * RS_H + (size_t)(tid >> 1) * H_ + n0 + (tid & 1) * 8, v);
            }
            vm_drain();
            signal_flag(fL1 + (size_t)(t + 1) * 64 + j);   // sync3
            if (t == T_ - 1 && kh == 0) {
                #pragma unroll
                for (int r = 0; r < 4; ++r)
                    out[(size_t)B_ * T_ * D_ + (size_t)(m0 + q * 4 + r) * H_ + n] = hv[r];
            }
        }
    } else {
        // =============== est/impute blocks ===============
        const int e  = bx - NL0 - NL1;
        const int d0 = e * 16;
        const int dd = d0 + r16;
        const float bo_ = (kh == 0) ? bout[dd] : 0.f;
        for (int t = 0; t < T_; ++t) {
            float xv[4], mv[4];
            if (kh == 0) {   // prefetch inputs before waiting
                #pragma unroll
                for (int r = 0; r < 4; ++r) {
                    int bb = m0 + q * 4 + r;
                    xv[r] = X [(size_t)(bb * T_ + t) * D_ + dd];
                    mv[r] = Mm[(size_t)(bb * T_ + t) * D_ + dd];
                }
            }
            asm volatile("" ::: "memory");
            poll32(fL1 + (size_t)t * 64, kh);         // my half of h(t-1)
            floatx4 a = {0.f,0.f,0.f,0.f};
            const unsigned short* aB = hR + (size_t)t * RS_H + (m0 + r16) * H_ + q * 8;
            short8 af[16];
            #pragma unroll
            for (int k = 0; k < 16; ++k) af[k] = *(const short8*)(aB + (kh * 16 + k) * 32);
            #pragma unroll
            for (int k = 0; k < 16; ++k)
                a = MFMA(af[k], *(const short8*)(lfrag + (kh * 16 + k) * 512), a, 0,0,0);
            if (kh == 1) {
                float* z = redZ + ((size_t)mt * 64 + lane) * 12;
                #pragma unroll
                for (int r = 0; r < 4; ++r) z[r] = a[r];
            }
            __syncthreads();                          // sync1
            float estv[4];
            if (kh == 0) {
                const float* z = redZ + ((size_t)mt * 64 + lane) * 12;
                #pragma unroll
                for (int r = 0; r < 4; ++r) {
                    estv[r] = a[r] + z[r] + bo_;
                    float imp = mv[r] * xv[r] + (1.0f - mv[r]) * estv[r];
                    ldsT[(m0 + q * 4 + r) * 16 + r16] = f2bf(imp);
                }
            }
            __syncthreads();                          // sync2
            if (tid < 128) {
                short8 v = *(const short8*)(ldsT + tid * 8);
                st16_sc(impR + (size_t)t * RS_IMP + (size_t)(tid >> 1) * D_ + d0 + (tid & 1) * 8, v);
            }
            vm_drain();
            signal_flag(fE + (size_t)t * 16 + e);     // sync3
            if (t >= 1 && kh == 0) {
                #pragma unroll
                for (int r = 0; r < 4; ++r)
                    out[(size_t)((m0 + q * 4 + r) * T_ + (t - 1)) * D_ + dd] = estv[r];
            }
        }
        // final projection: est from h(T-1) (slot T_) -> out[:, T-1, :]
        poll32(fL1 + (size_t)T_ * 64, kh);
        floatx4 a = {0.f,0.f,0.f,0.f};
        const unsigned short* aB = hR + (size_t)T_ * RS_H + (m0 + r16) * H_ + q * 8;
        short8 af[16];
        #pragma unroll
        for (int k = 0; k < 16; ++k) af[k] = *(const short8*)(aB + (kh * 16 + k) * 32);
        #pragma unroll
        for (int k = 0; k < 16; ++k)
            a = MFMA(af[k], *(const short8*)(lfrag + (kh * 16 + k) * 512), a, 0,0,0);
        if (kh == 1) {
            float* z = redZ + ((size_t)mt * 64 + lane) * 12;
            #pragma unroll
            for (int r = 0; r < 4; ++r) z[r] = a[r];
        }
        __syncthreads();
        if (kh == 0) {
            const float* z = redZ + ((size_t)mt * 64 + lane) * 12;
            #pragma unroll
            for (int r = 0; r < 4; ++r)
                out[(size_t)((m0 + q * 4 + r) * T_ + (T_ - 1)) * D_ + dd] = a[r] + z[r] + bo_;
        }
    }
}

extern "C" void kernel_launch(void* const* d_in, const int* in_sizes, int n_in,
                              void* d_out, int out_size, void* d_ws, size_t ws_size,
                              hipStream_t stream) {
    const float* X    = (const float*)d_in[0];
    const float* Mm   = (const float*)d_in[1];
    const float* Wih0 = (const float*)d_in[2];
    const float* Whh0 = (const float*)d_in[3];
    const float* bih0 = (const float*)d_in[4];
    const float* bhh0 = (const float*)d_in[5];
    const float* Wih1 = (const float*)d_in[6];
    const float* Whh1 = (const float*)d_in[7];
    const float* bih1 = (const float*)d_in[8];
    const float* bhh1 = (const float*)d_in[9];
    const float* Wout = (const float*)d_in[10];
    const float* bout = (const float*)d_in[11];
    float* out = (float*)d_out;

    // ring workspace (256B aligned); no init needed: flags compare ==1 vs
    // 0xAA poison, hR slot 0 zeroed in-kernel by l1 blocks.
    char* ws = (char*)d_ws;
    size_t off = 0;
    auto alloc = [&](size_t bytes) { char* p = ws + off; off = (off + bytes + 255) & ~(size_t)255; return p; };
    unsigned short* hR   = (unsigned short*)alloc((size_t)(T_ + 1) * RS_H * 2);
    unsigned short* h0R  = (unsigned short*)alloc((size_t)T_ * RS_H * 2);
    unsigned short* impR = (unsigned short*)alloc((size_t)T_ * RS_IMP * 2);
    int*            fL1  = (int*)alloc((size_t)(T_ + 1) * 64 * 4);
    int*            fL0  = (int*)alloc((size_t)T_ * 64 * 4);
    int*            fE   = (int*)alloc((size_t)T_ * 16 * 4);

    k_fused<<<NBLK, 512, 0, stream>>>(Wih0, Whh0, bih0, bhh0, Wih1, Whh1, bih1, bhh1,
                                      Wout, bout, X, Mm,
                                      hR, h0R, impR, fL1, fL0, fE, out);
}

// Round 9
// 2644.922 us; speedup vs baseline: 1.1301x; 1.1301x over previous
//
#include <hip/hip_runtime.h>
#include <math.h>

// MultiRNNCell: 2-layer LSTM-imputation scan. B=64, T=128, D=256, H=1024.
// R8 = R6 skeleton + XCD-staggered cooperative first-touch.
// Diagnosis R3-R7: per-hop cost is the consumer bulk pull of h/h0 (128 KB =
// 1024 lines) at HBM-miss RT (~900cyc) under a per-CU outstanding-miss cap
// (~64) => ~14K cyc/hop, AND all 8 XCDs miss the same lines simultaneously
// (dup HBM fetches, FETCH_SIZE evidence). Fix: consumer K-loops start at a
// rotated offset rot=(bx>>3)&7 (blocks with equal bx%8 share an XCD), so the
// 8 same-XCD consumers first-touch disjoint eighths of the slot; siblings'
// fills land in the shared XCD L2 and the rest of the pull hits L2.
//  - ring buffers (fresh addresses/step) -> plain cached consumer loads, no
//    fences anywhere; producers sc0 sc1 write-through + vmcnt drain; flags
//    relaxed agent ==1 vs 0xAA poison (no init); single dispatch.
// 144 blocks x 256 thr, 120KB LDS -> 1 block/CU. Dead forget gate removed;
// layer1 weight fold W1 = Wih1+Whh1.

#define B_ 64
#define T_ 128
#define D_ 256
#define H_ 1024

#define NL0 64
#define NL1 64
#define NEST 16
#define NBLK (NL0 + NL1 + NEST)   // 144

#define KS0 40          // layer0 frag ksteps: 0-7 imputed (D=256), 8-39 h (H=1024)
#define KS1 32          // layer1 ksteps (H=1024)
#define KSE 32          // est ksteps (H=1024)

#define RS_H   ((size_t)B_ * H_)   // 128 KB per ring slot
#define RS_IMP ((size_t)B_ * D_)   // 32 KB per ring slot

typedef __attribute__((ext_vector_type(8))) short short8;   // 8 bf16
typedef __attribute__((ext_vector_type(4))) float floatx4;  // MFMA C/D

__device__ __forceinline__ unsigned short f2bf(float x) {
    union { float f; unsigned u; } v; v.f = x;
    unsigned r = v.u + 0x7fffu + ((v.u >> 16) & 1u);  // RNE
    return (unsigned short)(r >> 16);
}
__device__ __forceinline__ float sigmoidf_(float x) { return 1.0f / (1.0f + expf(-x)); }

// write-through 2B store to the MALL coherence point (bypasses L1+L2)
__device__ __forceinline__ void st_short_sc(unsigned short* p, unsigned v) {
    asm volatile("global_store_short %0, %1, off sc0 sc1"
                 :: "v"(p), "v"(v) : "memory");
}
__device__ __forceinline__ void vm_drain() {
    asm volatile("s_waitcnt vmcnt(0)" ::: "memory");
}

// Wait until this step's flag row flags[0..P) all == 1 (ring flags: fresh row
// per step; 0xAA poison never equals 1 => no initialization needed).
__device__ __forceinline__ void wait_ready(const int* flags, int P) {
    if ((int)threadIdx.x < P) {
        while (__hip_atomic_load(flags + threadIdx.x, __ATOMIC_RELAXED,
                                 __HIP_MEMORY_SCOPE_AGENT) != 1) {}
    }
    __syncthreads();
}
__device__ __forceinline__ void signal_flag(int* flag) {
    __syncthreads();    // all waves' sc1 stores drained (vm_drain) before this
    if (threadIdx.x == 0)
        __hip_atomic_store(flag, 1, __ATOMIC_RELAXED, __HIP_MEMORY_SCOPE_AGENT);
}

#define MFMA __builtin_amdgcn_mfma_f32_16x16x32_bf16

__global__ __launch_bounds__(256, 1) void k_fused(
    const float* __restrict__ Wih0, const float* __restrict__ Whh0,
    const float* __restrict__ bih0, const float* __restrict__ bhh0,
    const float* __restrict__ Wih1, const float* __restrict__ Whh1,
    const float* __restrict__ bih1, const float* __restrict__ bhh1,
    const float* __restrict__ Wout, const float* __restrict__ bout,
    const float* __restrict__ X, const float* __restrict__ Mm,
    unsigned short* __restrict__ hR,    // (T_+1) slots
    unsigned short* __restrict__ h0R,   // T_ slots
    unsigned short* __restrict__ impR,  // T_ slots
    int* __restrict__ fL1, int* __restrict__ fL0, int* __restrict__ fE,
    float* __restrict__ out)
{
    __shared__ unsigned short ldsW[3 * KS0 * 64 * 8];   // 120 KB weight frags

    const int tid  = threadIdx.x;
    const int lane = tid & 63;
    const int wv   = tid >> 6;       // wave id = m-tile (16 batch rows)
    const int r16  = lane & 15, q = lane >> 4;
    const int bx   = blockIdx.x;
    const int m0   = wv * 16;
    const int rot  = (bx >> 3) & 7;  // XCD-local stagger (bx%8 = XCD id)
    const int rot4 = rot * 4;        // chunk of 4 ksteps out of 32
    const unsigned short* lfrag = ldsW + lane * 8;   // + fragIdx*512

    // ---- one-time: fp32 weights -> bf16 LDS fragment order ----
    if (bx < NL0) {
        int n0 = bx * 16;
        for (int idx = wv; idx < 3 * KS0; idx += 4) {
            int gi = idx / KS0, k = idx % KS0;
            int grow = (gi == 0) ? 0 : (gi == 1 ? 2 * H_ : 3 * H_);
            int row = grow + n0 + r16;
            const float* src = (k < 8) ? (Wih0 + (size_t)row * D_ + k * 32 + q * 8)
                                       : (Whh0 + (size_t)row * H_ + (k - 8) * 32 + q * 8);
            short8 w;
            #pragma unroll
            for (int j = 0; j < 8; ++j) w[j] = (short)f2bf(src[j]);
            *(short8*)(ldsW + ((size_t)idx * 64 + lane) * 8) = w;
        }
    } else if (bx < NL0 + NL1) {
        int n0 = (bx - NL0) * 16;
        for (int idx = wv; idx < 3 * KS1; idx += 4) {
            int gi = idx / KS1, k = idx % KS1;
            int grow = (gi == 0) ? 0 : (gi == 1 ? 2 * H_ : 3 * H_);
            size_t o = (size_t)(grow + n0 + r16) * H_ + k * 32 + q * 8;
            short8 w;
            #pragma unroll
            for (int j = 0; j < 8; ++j) w[j] = (short)f2bf(Wih1[o + j] + Whh1[o + j]);
            *(short8*)(ldsW + ((size_t)idx * 64 + lane) * 8) = w;
        }
    } else {
        int d0 = (bx - NL0 - NL1) * 16;
        for (int idx = wv; idx < KSE; idx += 4) {
            const float* src = Wout + (size_t)(d0 + r16) * H_ + idx * 32 + q * 8;
            short8 w;
            #pragma unroll
            for (int j = 0; j < 8; ++j) w[j] = (short)f2bf(src[j]);
            *(short8*)(ldsW + ((size_t)idx * 64 + lane) * 8) = w;
        }
    }
    __syncthreads();

    if (bx < NL0) {
        // =============== layer-0 blocks ===============
        const int n = bx * 16 + r16;
        const float bi = bih0[n] + bhh0[n];
        const float bg = bih0[2 * H_ + n] + bhh0[2 * H_ + n];
        const float bo = bih0[3 * H_ + n] + bhh0[3 * H_ + n];
        for (int t = 0; t < T_; ++t) {
            wait_ready(fL1 + (size_t)t * 64, 64);     // h(t-1) = slot t ready
            floatx4 ai = {0.f,0.f,0.f,0.f}, ag = ai, ao = ai;
            {   // h-part, rotated start -> cooperative XCD first-touch
                const unsigned short* aB = hR + (size_t)t * RS_H + (m0 + r16) * H_ + q * 8;
                #pragma unroll
                for (int k = 0; k < 32; ++k) {
                    int idx = (k + rot4) & 31;
                    short8 a = *(const short8*)(aB + idx * 32);
                    ai = MFMA(a, *(const short8*)(lfrag + (0*KS0 + 8 + idx)*512), ai, 0,0,0);
                    ag = MFMA(a, *(const short8*)(lfrag + (1*KS0 + 8 + idx)*512), ag, 0,0,0);
                    ao = MFMA(a, *(const short8*)(lfrag + (2*KS0 + 8 + idx)*512), ao, 0,0,0);
                }
            }
            wait_ready(fE + (size_t)t * 16, 16);      // imputed(t) ready
            {   // imputed part (rotated by single ksteps)
                const unsigned short* aB = impR + (size_t)t * RS_IMP + (m0 + r16) * D_ + q * 8;
                #pragma unroll
                for (int k = 0; k < 8; ++k) {
                    int idx = (k + rot) & 7;
                    short8 a = *(const short8*)(aB + idx * 32);
                    ai = MFMA(a, *(const short8*)(lfrag + (0*KS0 + idx)*512), ai, 0,0,0);
                    ag = MFMA(a, *(const short8*)(lfrag + (1*KS0 + idx)*512), ag, 0,0,0);
                    ao = MFMA(a, *(const short8*)(lfrag + (2*KS0 + idx)*512), ao, 0,0,0);
                }
                unsigned short* h0S = h0R + (size_t)t * RS_H;
                #pragma unroll
                for (int r = 0; r < 4; r++) {
                    int bb = m0 + q * 4 + r;
                    float c = sigmoidf_(ai[r] + bi) * tanhf(ag[r] + bg);
                    float h = sigmoidf_(ao[r] + bo) * tanhf(c);
                    st_short_sc(&h0S[bb * H_ + n], (unsigned)f2bf(h));
                }
            }
            vm_drain();
            signal_flag(fL0 + (size_t)t * 64 + bx);
        }
    } else if (bx < NL0 + NL1) {
        // =============== layer-1 blocks ===============
        const int j = bx - NL0;
        const int n = j * 16 + r16;
        const float bi = bih1[n] + bhh1[n];
        const float bg = bih1[2 * H_ + n] + bhh1[2 * H_ + n];
        const float bo = bih1[3 * H_ + n] + bhh1[3 * H_ + n];
        // h(-1) = 0 -> zeros into hR slot 0, then flag it
        #pragma unroll
        for (int r = 0; r < 4; r++)
            st_short_sc(&hR[(size_t)(m0 + q * 4 + r) * H_ + n], 0);
        vm_drain();
        signal_flag(fL1 + j);
        for (int t = 0; t < T_; ++t) {
            wait_ready(fL0 + (size_t)t * 64, 64);     // h0(t) ready
            floatx4 li = {0.f,0.f,0.f,0.f}, lg = li, lo = li;
            const unsigned short* aB = h0R + (size_t)t * RS_H + (m0 + r16) * H_ + q * 8;
            #pragma unroll
            for (int k = 0; k < KS1; ++k) {
                int idx = (k + rot4) & 31;
                short8 a = *(const short8*)(aB + idx * 32);
                li = MFMA(a, *(const short8*)(lfrag + (0*KS1 + idx)*512), li, 0,0,0);
                lg = MFMA(a, *(const short8*)(lfrag + (1*KS1 + idx)*512), lg, 0,0,0);
                lo = MFMA(a, *(const short8*)(lfrag + (2*KS1 + idx)*512), lo, 0,0,0);
            }
            float hv[4];
            unsigned short* hS = hR + (size_t)(t + 1) * RS_H;
            #pragma unroll
            for (int r = 0; r < 4; r++) {
                int bb = m0 + q * 4 + r;
                float c = sigmoidf_(li[r] + bi) * tanhf(lg[r] + bg);
                hv[r] = sigmoidf_(lo[r] + bo) * tanhf(c);
                st_short_sc(&hS[bb * H_ + n], (unsigned)f2bf(hv[r]));
            }
            vm_drain();
            signal_flag(fL1 + (size_t)(t + 1) * 64 + j);
            if (t == T_ - 1) {
                #pragma unroll
                for (int r = 0; r < 4; r++)
                    out[(size_t)B_ * T_ * D_ + (size_t)(m0 + q * 4 + r) * H_ + n] = hv[r];
            }
        }
    } else {
        // =============== est/impute blocks ===============
        const int e  = bx - NL0 - NL1;
        const int dd = e * 16 + r16;
        const float bo_ = bout[dd];
        for (int t = 0; t < T_; ++t) {
            float xv[4], mv[4];   // prefetch inputs before waiting
            #pragma unroll
            for (int r = 0; r < 4; r++) {
                int bb = m0 + q * 4 + r;
                xv[r] = X [(size_t)(bb * T_ + t) * D_ + dd];
                mv[r] = Mm[(size_t)(bb * T_ + t) * D_ + dd];
            }
            asm volatile("" ::: "memory");
            wait_ready(fL1 + (size_t)t * 64, 64);     // h(t-1) = slot t ready
            floatx4 a0 = {0.f,0.f,0.f,0.f}, a1 = a0;
            const unsigned short* aB = hR + (size_t)t * RS_H + (m0 + r16) * H_ + q * 8;
            #pragma unroll
            for (int k = 0; k < 16; ++k) {
                int i0 = (2*k     + rot4) & 31;
                int i1 = (2*k + 1 + rot4) & 31;
                short8 x0 = *(const short8*)(aB + i0 * 32);
                short8 x1 = *(const short8*)(aB + i1 * 32);
                a0 = MFMA(x0, *(const short8*)(lfrag + i0*512), a0, 0,0,0);
                a1 = MFMA(x1, *(const short8*)(lfrag + i1*512), a1, 0,0,0);
            }
            float estv[4];
            unsigned short* iS = impR + (size_t)t * RS_IMP;
            #pragma unroll
            for (int r = 0; r < 4; r++) {
                int bb = m0 + q * 4 + r;
                estv[r] = a0[r] + a1[r] + bo_;
                st_short_sc(&iS[bb * D_ + dd],
                            (unsigned)f2bf(mv[r] * xv[r] + (1.0f - mv[r]) * estv[r]));
            }
            vm_drain();
            signal_flag(fE + (size_t)t * 16 + e);
            if (t >= 1) {
                #pragma unroll
                for (int r = 0; r < 4; r++) {
                    int bb = m0 + q * 4 + r;
                    out[(size_t)(bb * T_ + (t - 1)) * D_ + dd] = estv[r];
                }
            }
        }
        // final projection: est from h(T-1) (slot T_) -> out[:, T-1, :]
        wait_ready(fL1 + (size_t)T_ * 64, 64);
        floatx4 a0 = {0.f,0.f,0.f,0.f}, a1 = a0;
        const unsigned short* aB = hR + (size_t)T_ * RS_H + (m0 + r16) * H_ + q * 8;
        #pragma unroll
        for (int k = 0; k < 16; ++k) {
            int i0 = (2*k     + rot4) & 31;
            int i1 = (2*k + 1 + rot4) & 31;
            short8 x0 = *(const short8*)(aB + i0 * 32);
            short8 x1 = *(const short8*)(aB + i1 * 32);
            a0 = MFMA(x0, *(const short8*)(lfrag + i0*512), a0, 0,0,0);
            a1 = MFMA(x1, *(const short8*)(lfrag + i1*512), a1, 0,0,0);
        }
        #pragma unroll
        for (int r = 0; r < 4; r++) {
            int bb = m0 + q * 4 + r;
            out[(size_t)(bb * T_ + (T_ - 1)) * D_ + dd] = a0[r] + a1[r] + bo_;
        }
    }
}

extern "C" void kernel_launch(void* const* d_in, const int* in_sizes, int n_in,
                              void* d_out, int out_size, void* d_ws, size_t ws_size,
                              hipStream_t stream) {
    const float* X    = (const float*)d_in[0];
    const float* Mm   = (const float*)d_in[1];
    const float* Wih0 = (const float*)d_in[2];
    const float* Whh0 = (const float*)d_in[3];
    const float* bih0 = (const float*)d_in[4];
    const float* bhh0 = (const float*)d_in[5];
    const float* Wih1 = (const float*)d_in[6];
    const float* Whh1 = (const float*)d_in[7];
    const float* bih1 = (const float*)d_in[8];
    const float* bhh1 = (const float*)d_in[9];
    const float* Wout = (const float*)d_in[10];
    const float* bout = (const float*)d_in[11];
    float* out = (float*)d_out;

    // ring workspace (256B aligned); no init: flags compare ==1 vs 0xAA
    // poison, hR slot 0 zeroed in-kernel by l1 blocks.
    char* ws = (char*)d_ws;
    size_t off = 0;
    auto alloc = [&](size_t bytes) { char* p = ws + off; off = (off + bytes + 255) & ~(size_t)255; return p; };
    unsigned short* hR   = (unsigned short*)alloc((size_t)(T_ + 1) * RS_H * 2);
    unsigned short* h0R  = (unsigned short*)alloc((size_t)T_ * RS_H * 2);
    unsigned short* impR = (unsigned short*)alloc((size_t)T_ * RS_IMP * 2);
    int*            fL1  = (int*)alloc((size_t)(T_ + 1) * 64 * 4);
    int*            fL0  = (int*)alloc((size_t)T_ * 64 * 4);
    int*            fE   = (int*)alloc((size_t)T_ * 16 * 4);

    k_fused<<<NBLK, 256, 0, stream>>>(Wih0, Whh0, bih0, bhh0, Wih1, Whh1, bih1, bhh1,
                                      Wout, bout, X, Mm,
                                      hR, h0R, impR, fL1, fL0, fE, out);
}